// Round 11
// baseline (96.752 us; speedup 1.0000x reference)
//
#include <hip/hip_runtime.h>
#include <math.h>

#define H_   23
#define W_   23
#define P_   529
#define TH_  0.05f
#define NC   9            // ceil(529/64) chunks per wave
#define CAP  96           // max compacted peaks (geometric max is 64 for strict peaks)
#define WPB  4            // waves (batch elements) per block
#define NTHR (WPB * 64)
// per-wave LDS floats: [r 529+pad3][m 529+pad3][wt 112][ps 96] = 1272 (16B-aligned partition)
#define WFLO 1272

typedef float f2_t __attribute__((ext_vector_type(2)));
typedef float f4_t __attribute__((ext_vector_type(4)));
typedef int   i4_t __attribute__((ext_vector_type(4)));

// wave-synchronous fence: per-wave LDS ops execute in program order across the
// whole wave (SIMD lockstep); this only stops compiler reordering across phases.
#define WSYNC() do { asm volatile("" ::: "memory"); __builtin_amdgcn_wave_barrier(); } while (0)

__global__ __launch_bounds__(NTHR, 8) void peak_kernel(
    const float* __restrict__ tscores,  // [2,B,P]
    const float* __restrict__ anno,     // [1,B,P]
    const float* __restrict__ W1, const float* __restrict__ b1,
    const float* __restrict__ g1, const float* __restrict__ be1,
    const float* __restrict__ m1, const float* __restrict__ v1,
    const float* __restrict__ W2, const float* __restrict__ b2,
    const float* __restrict__ g2, const float* __restrict__ be2,
    const float* __restrict__ m2, const float* __restrict__ v2,
    const float* __restrict__ W3, const float* __restrict__ b3,
    float* __restrict__ out, int B)
{
    const int t  = threadIdx.x;
    const int l  = t & 63;
    const int wv = t >> 6;
    const int b  = blockIdx.x * WPB + wv;

    __shared__ float lds[WPB * WFLO];
    float* r   = lds + wv * WFLO;    // [529] rowmax; overlays: cs/cp/rk; later ri
    float* m   = r + 532;            // [529] raw map (old, then cur — kept for out_s)
    float* wt  = r + 1064;           // [112] folded MLP weights (16B-aligned)
    float* ps  = r + 1176;           // [96]  pred staged by slot
    float* cs  = r;                  // [100] compacted scores   (16B-aligned)
    int*   cp  = (int*)(r + 104);    // [100] compacted positions (16B-aligned)
    int*   rk  = (int*)(r + 208);    // [96]  rank of compacted entry
    int*   ri  = (int*)r;            // [529] inv: slot -> position (overlay, last)

    const unsigned long long ltm = (1ull << l) - 1ull;

    // ---------------- fold BN into linear weights (wave-private, in LDS) ----------
    {
        int o = l >> 3;
        float sc2o = g2[o] / sqrtf(v2[o] + 1e-5f);
        wt[24 + l] = W2[l] * sc2o;                       // w2f[64]
        if (l < 8) {
            float sc1 = g1[l] / sqrtf(v1[l] + 1e-5f);
            wt[2*l]     = W1[2*l] * sc1;                 // w1f[16]
            wt[2*l + 1] = W1[2*l + 1] * sc1;
            wt[16 + l]  = (b1[l] - m1[l]) * sc1 + be1[l];// b1f[8]
            float sc2 = g2[l] / sqrtf(v2[l] + 1e-5f);
            wt[88 + l]  = (b2[l] - m2[l]) * sc2 + be2[l];// b2f[8]
            wt[96 + l]  = W3[l];                         // w3f[8]
            if (l == 0) wt[104] = b3[0];
        }
    }

    // ---------------- issue global loads early ----------------
    const float* yrow = anno + (size_t)b * P_;
    const float* sold = tscores + (size_t)b * P_;
    const float* scur = tscores + (size_t)B * P_ + (size_t)b * P_;
    float ao[NC], so[NC], sc[NC];
    #pragma unroll
    for (int c = 0; c < NC; c++) { int p = 64*c + l; ao[c] = (p < P_) ? yrow[p] : -INFINITY; }
    #pragma unroll
    for (int c = 0; c < NC; c++) { int p = 64*c + l; so[c] = (p < P_) ? sold[p] : 0.f; }
    #pragma unroll
    for (int c = 0; c < NC; c++) { int p = 64*c + l; sc[c] = (p < P_) ? scur[p] : 0.f; }

    // ---------------- anno argmax (first max wins) ----------------
    float bv = -INFINITY; int bi = 0x7fffffff;
    #pragma unroll
    for (int c = 0; c < NC; c++) {
        int p = 64*c + l;
        if (p < P_ && ao[c] > bv) { bv = ao[c]; bi = p; }
    }
    #pragma unroll
    for (int d = 32; d > 0; d >>= 1) {
        float ov = __shfl_xor(bv, d); int oi = __shfl_xor(bi, d);
        if (ov > bv || (ov == bv && oi < bi)) { bv = ov; bi = oi; }
    }
    const int gy = bi / W_, gx = bi - (bi / W_) * W_;

    // ---------------- helpers (round-6 guarded windows) ----------------
    auto stage = [&](const float* v) {
        #pragma unroll
        for (int c = 0; c < NC; c++) {
            int p = 64*c + l;
            if (p < P_) m[p] = v[c];
        }
    };
    auto rowmax = [&]() {
        #pragma unroll
        for (int c = 0; c < NC; c++) {
            int p = 64*c + l;
            if (p < P_) {
                int y = p / W_, x = p - (p / W_) * W_;
                const float* row = &m[y * W_];
                float mx = row[x];
                if (x >= 1)      mx = fmaxf(mx, row[x-1]);
                if (x >= 2)      mx = fmaxf(mx, row[x-2]);
                if (x <= W_-2)   mx = fmaxf(mx, row[x+1]);
                if (x <= W_-3)   mx = fmaxf(mx, row[x+2]);
                r[p] = mx;
            }
        }
    };
    auto colmax = [&](int c) {
        int p = 64*c + l;
        int y = p / W_;
        float sm = r[p];
        if (y >= 1)    sm = fmaxf(sm, r[p - W_]);
        if (y >= 2)    sm = fmaxf(sm, r[p - 2*W_]);
        if (y <= H_-2) sm = fmaxf(sm, r[p + W_]);
        if (y <= H_-3) sm = fmaxf(sm, r[p + 2*W_]);
        return sm;
    };

    // ---------------- OLD map: peaks + stats + nearest-to-gc ----------------
    stage(so);
    WSYNC();
    rowmax();
    WSYNC();
    float So = 0.f, Mor = 0.f, Moc = 0.f;
    float nd2 = INFINITY, ns = -INFINITY; int np = 0;
    #pragma unroll
    for (int c = 0; c < NC; c++) {
        int p = 64*c + l;
        if (p < P_) {
            int y = p / W_, x = p - (p / W_) * W_;
            float s = so[c];
            float sm = colmax(c);
            if (s == sm && s > TH_) {
                So += s; Mor += s * (float)y; Moc += s * (float)x;
                int dy = gy - y, dx = gx - x;
                float d2 = (float)(dy*dy + dx*dx);
                if (d2 < nd2 || (d2 == nd2 && (s > ns || (s == ns && p < np)))) {
                    nd2 = d2; ns = s; np = p;
                }
            }
        }
    }
    #pragma unroll
    for (int d = 32; d > 0; d >>= 1) {
        So += __shfl_xor(So, d); Mor += __shfl_xor(Mor, d); Moc += __shfl_xor(Moc, d);
        float od2 = __shfl_xor(nd2, d), os = __shfl_xor(ns, d); int op = __shfl_xor(np, d);
        if (od2 < nd2 || (od2 == nd2 && (os > ns || (os == ns && op < np)))) {
            nd2 = od2; ns = os; np = op;
        }
    }
    const int cy = np / W_, cx = np - (np / W_) * W_;
    const float foldr = So * (float)cy - Mor;   // f_old (exactly 0 when no peaks)
    const float foldc = So * (float)cx - Moc;

    // ---------------- CUR map: peaks + stats (m keeps cur scores) ----------------
    WSYNC();
    stage(sc);
    WSYNC();
    rowmax();
    WSYNC();
    float Sc = 0.f, Mcr = 0.f, Mcc = 0.f;
    int vb = 0;
    #pragma unroll
    for (int c = 0; c < NC; c++) {
        int p = 64*c + l;
        if (p < P_) {
            int y = p / W_, x = p - (p / W_) * W_;
            float s = sc[c];
            float sm = colmax(c);
            if (s == sm && s > TH_) {
                vb |= 1 << c;
                Sc += s; Mcr += s * (float)y; Mcc += s * (float)x;
            }
        }
    }
    #pragma unroll
    for (int d = 32; d > 0; d >>= 1) {
        Sc += __shfl_xor(Sc, d); Mcr += __shfl_xor(Mcr, d); Mcc += __shfl_xor(Mcc, d);
    }
    WSYNC();   // rowmax region dead; reuse as cs/cp/rk

    // ---------------- compaction via ballot ----------------
    int K = 0;
    int nb[NC];                       // #valid strictly before p, per chunk
    #pragma unroll
    for (int c = 0; c < NC; c++) {
        bool v = (vb >> c) & 1;
        unsigned long long bt = __ballot(v);
        int my = K + __popcll(bt & ltm);
        nb[c] = my;
        if (v && my < CAP) { cs[my] = sc[c]; cp[my] = 64*c + l; }
        K += __popcll(bt);
    }
    const int Kc = K > CAP ? CAP : K;
    // pad cs/cp to a multiple of 4 so the rank loop can read b128 unconditionally
    if (l == 0) {
        int e = (Kc + 3) & ~3;
        for (int j = Kc; j < e; j++) { cs[j] = -INFINITY; cp[j] = 0x7fffffff; }
    }
    WSYNC();

    // ---------------- rank compacted peaks (score desc, pos asc), float4 reads ----
    for (int i = l; i < Kc; i += 64) {
        float si = cs[i]; int pi = cp[i]; int rr = 0;
        for (int j = 0; j < Kc; j += 4) {
            f4_t s4 = *(const f4_t*)&cs[j];
            i4_t p4 = *(const i4_t*)&cp[j];
            #pragma unroll
            for (int q = 0; q < 4; q++)
                rr += (s4[q] > si || (s4[q] == si && p4[q] < pi)) ? 1 : 0;
        }
        rk[i] = rr;
    }
    WSYNC();

    // ---------------- MLP over compacted peaks only (float4 weight broadcasts) ----
    auto mlp = [&](int i, float& pv, int& rko) {
        int p = cp[i];
        float s = cs[i];
        rko = rk[i];
        int y = p / W_, x = p - (p / W_) * W_;
        float fcr = Sc * (float)y - Mcr;
        float fcc = Sc * (float)x - Mcc;
        float dr = foldr - fcr, dc = foldc - fcc;
        float err = sqrtf(fmaxf(dr*dr + dc*dc, 1e-24f));
        const f4_t* wq = (const f4_t*)wt;
        f4_t w1a = wq[0], w1b = wq[1], w1c = wq[2], w1d = wq[3];   // w1f[16]
        f4_t b1a = wq[4], b1b = wq[5];                             // b1f[8]
        float h1[8];
        h1[0] = fmaxf(fmaf(err, w1a[0], fmaf(s, w1a[1], b1a[0])), 0.f);
        h1[1] = fmaxf(fmaf(err, w1a[2], fmaf(s, w1a[3], b1a[1])), 0.f);
        h1[2] = fmaxf(fmaf(err, w1b[0], fmaf(s, w1b[1], b1a[2])), 0.f);
        h1[3] = fmaxf(fmaf(err, w1b[2], fmaf(s, w1b[3], b1a[3])), 0.f);
        h1[4] = fmaxf(fmaf(err, w1c[0], fmaf(s, w1c[1], b1b[0])), 0.f);
        h1[5] = fmaxf(fmaf(err, w1c[2], fmaf(s, w1c[3], b1b[1])), 0.f);
        h1[6] = fmaxf(fmaf(err, w1d[0], fmaf(s, w1d[1], b1b[2])), 0.f);
        h1[7] = fmaxf(fmaf(err, w1d[2], fmaf(s, w1d[3], b1b[3])), 0.f);
        f4_t b2a = wq[22], b2b = wq[23];                           // b2f[8]  (wt+88)
        f4_t w3a = wq[24], w3b = wq[25];                           // w3f[8]  (wt+96)
        float pred = wt[104];
        #pragma unroll
        for (int o = 0; o < 8; o++) {
            f4_t wa = wq[6 + 2*o], wb = wq[7 + 2*o];               // w2f row o (wt+24)
            float z = (o < 4) ? b2a[o & 3] : b2b[o & 3];
            z = fmaf(h1[0], wa[0], z); z = fmaf(h1[1], wa[1], z);
            z = fmaf(h1[2], wa[2], z); z = fmaf(h1[3], wa[3], z);
            z = fmaf(h1[4], wb[0], z); z = fmaf(h1[5], wb[1], z);
            z = fmaf(h1[6], wb[2], z); z = fmaf(h1[7], wb[3], z);
            float w3o = (o < 4) ? w3a[o & 3] : w3b[o & 3];
            pred = fmaf(fmaxf(z, 0.f), w3o, pred);
        }
        pv = pred;
    };
    float pv0 = 0.f, pv1 = 0.f; int rk0 = -1, rk1 = -1;
    if (l < Kc)      mlp(l, pv0, rk0);
    if (64 + l < Kc) mlp(64 + l, pv1, rk1);
    if (rk0 >= 0) ps[rk0] = pv0;
    if (rk1 >= 0) ps[rk1] = pv1;

    // ---------------- slot per position (reads rk), then inv scatter ----------------
    int slot[NC];
    #pragma unroll
    for (int c = 0; c < NC; c++) {
        int p = 64*c + l;
        if (p < P_) {
            bool v = (vb >> c) & 1;
            int n = nb[c];
            slot[c] = v ? ((n < CAP) ? rk[n] : n) : (K + p - n);
        }
    }
    WSYNC();                      // rk reads done before ri overlays r
    #pragma unroll
    for (int c = 0; c < NC; c++) {
        int p = 64*c + l;
        if (p < P_) ri[slot[c]] = p;
    }
    WSYNC();

    // ---------------- linear, coalesced output ----------------
    const size_t BP = (size_t)B * P_;
    float* out_pred = out;
    float* out_c    = out + BP;        // [B,P,2]
    float* out_s    = out + 3 * BP;
    float* out_v    = out + 4 * BP;
    const size_t rowbase = (size_t)b * P_;

    #pragma unroll
    for (int c = 0; c < NC; c++) {
        int j = 64*c + l;
        if (j < P_) {
            int p = ri[j];
            int y = p / W_, x = p - (p / W_) * W_;
            bool val = j < K;
            float pv = (val && j < CAP) ? ps[j] : 0.f;
            float s  = m[p];
            f2_t co; co.x = (float)y; co.y = (float)x;
            out_pred[rowbase + j] = pv;
            ((f2_t*)out_c)[rowbase + j] = co;
            out_s[rowbase + j] = s;
            out_v[rowbase + j] = val ? 1.f : 0.f;
        }
    }
}

extern "C" void kernel_launch(void* const* d_in, const int* in_sizes, int n_in,
                              void* d_out, int out_size, void* d_ws, size_t ws_size,
                              hipStream_t stream) {
    const int B = in_sizes[0] / (2 * P_);
    hipLaunchKernelGGL(peak_kernel, dim3((B + WPB - 1) / WPB), dim3(NTHR), 0, stream,
        (const float*)d_in[0], (const float*)d_in[1],
        (const float*)d_in[2], (const float*)d_in[3], (const float*)d_in[4],
        (const float*)d_in[5], (const float*)d_in[6], (const float*)d_in[7],
        (const float*)d_in[8], (const float*)d_in[9], (const float*)d_in[10],
        (const float*)d_in[11], (const float*)d_in[12], (const float*)d_in[13],
        (const float*)d_in[14], (const float*)d_in[15],
        (float*)d_out, B);
}

// Round 13
// 89.509 us; speedup vs baseline: 1.0809x; 1.0809x over previous
//
#include <hip/hip_runtime.h>
#include <math.h>

#define H_   23
#define W_   23
#define P_   529
#define TH_  0.05f
#define NC   9            // output chunks: j = 64c + l
#define PC   5            // pair chunks:  q = 128c + 2l
#define CAP  96           // max compacted peaks
#define WPB  4            // waves (batch elements) per block
#define NTHR (WPB * 64)
#define WFLO 1176         // per-wave floats: r[532] m[532] wt[112]

typedef float f2_t  __attribute__((ext_vector_type(2)));
typedef float f2u_t __attribute__((ext_vector_type(2), aligned(4)));

// wave-synchronous fence: per-wave LDS ops execute in program order across the
// whole wave (SIMD lockstep); this only stops compiler reordering across phases.
#define WSYNC() do { asm volatile("" ::: "memory"); __builtin_amdgcn_wave_barrier(); } while (0)

__global__ __launch_bounds__(NTHR, 8) void peak_kernel(
    const float* __restrict__ tscores,  // [2,B,P]
    const float* __restrict__ anno,     // [1,B,P]
    const float* __restrict__ W1, const float* __restrict__ b1,
    const float* __restrict__ g1, const float* __restrict__ be1,
    const float* __restrict__ m1, const float* __restrict__ v1,
    const float* __restrict__ W2, const float* __restrict__ b2,
    const float* __restrict__ g2, const float* __restrict__ be2,
    const float* __restrict__ m2, const float* __restrict__ v2,
    const float* __restrict__ W3, const float* __restrict__ b3,
    float* __restrict__ out, int B)
{
    const int t  = threadIdx.x;
    const int l  = t & 63;
    const int wv = t >> 6;
    const int b  = blockIdx.x * WPB + wv;
    if (b >= B) return;   // safe: no block-wide barriers anywhere

    __shared__ float lds[WPB * WFLO];
    float* r  = lds + wv * WFLO;   // [532] rowmax; overlays: cs/cp/rk; later ri
    float* m  = r + 532;           // [532] cur map (for out_s gather)
    float* wt = r + 1064;          // [112] folded MLP weights; ps overlays after mlp
    float* cs = r;                 // [CAP] compacted scores        (overlay)
    int*   cp = (int*)(r + CAP);   // [CAP] compacted positions     (overlay)
    int*   rk = (int*)(r + 2*CAP); // [CAP] rank of compacted entry (overlay)
    int*   ri = (int*)r;           // [529] inv: slot -> position   (overlay, last)
    float* ps = wt;                // [96]  pred staged by slot     (overlay on wt)

    const unsigned long long ltm = (1ull << l) - 1ull;

    // ---------------- fold BN into linear weights (wave-private, r6 exact) -------
    {
        int o = l >> 3;
        float sc2o = g2[o] / sqrtf(v2[o] + 1e-5f);
        wt[24 + l] = W2[l] * sc2o;                       // w2f[64]
        if (l < 8) {
            float sc1 = g1[l] / sqrtf(v1[l] + 1e-5f);
            wt[2*l]     = W1[2*l] * sc1;                 // w1f[16]
            wt[2*l + 1] = W1[2*l + 1] * sc1;
            wt[16 + l]  = (b1[l] - m1[l]) * sc1 + be1[l];// b1f[8]
            float sc2 = g2[l] / sqrtf(v2[l] + 1e-5f);
            wt[88 + l]  = (b2[l] - m2[l]) * sc2 + be2[l];// b2f[8]
            wt[96 + l]  = W3[l];                         // w3f[8]
            if (l == 0) wt[104] = b3[0];
        }
    }

    const float* yrow = anno + (size_t)b * P_;
    const float* sold = tscores + (size_t)b * P_;
    const float* scur = tscores + (size_t)B * P_ + (size_t)b * P_;

    // ---------------- anno argmax (r6 exact, first max wins) ----------------
    float ao[NC];
    #pragma unroll
    for (int c = 0; c < NC; c++) { int p = 64*c + l; ao[c] = (p < P_) ? yrow[p] : -INFINITY; }
    float bv = -INFINITY; int bi = 0x7fffffff;
    #pragma unroll
    for (int c = 0; c < NC; c++) {
        int p = 64*c + l;
        if (p < P_ && ao[c] > bv) { bv = ao[c]; bi = p; }
    }
    #pragma unroll
    for (int d = 32; d > 0; d >>= 1) {
        float ov = __shfl_xor(bv, d); int oi = __shfl_xor(bi, d);
        if (ov > bv || (ov == bv && oi < bi)) { bv = ov; bi = oi; }
    }
    const int gy = bi / W_, gx = bi - (bi / W_) * W_;

    // ---------------- pair-vectorized row-max pass (global windows -> LDS r) ----
    auto rmpass = [&](const float* __restrict__ src, f2_t* bv2, bool stm) {
        #pragma unroll
        for (int c = 0; c < PC; c++) {
            int q = 128*c + 2*l;
            f2_t z; z.x = 0.f; z.y = 0.f; bv2[c] = z;
            if (q < P_) {
                int y0 = q / W_, x0 = q - y0 * W_;
                f2_t bq = *(const f2u_t*)(src + q);
                f2_t aq = bq, cq = bq;
                if (q >= 2)     aq = *(const f2u_t*)(src + q - 2);
                if (q + 2 < P_) cq = *(const f2u_t*)(src + q + 2);
                bool wrap = (x0 == W_ - 1);
                // position q (x0):   window {aq.x,aq.y,bq.x,bq.y,cq.x}
                float rm0 = bq.x;
                if (x0 >= 1)  rm0 = fmaxf(rm0, aq.y);
                if (x0 >= 2)  rm0 = fmaxf(rm0, aq.x);
                if (x0 <= 21) rm0 = fmaxf(rm0, bq.y);
                if (x0 <= 20) rm0 = fmaxf(rm0, cq.x);
                // position q+1 (x1 = wrap?0:x0+1): window {aq.y,bq.x,bq.y,cq.x,cq.y}
                float rm1 = bq.y;
                if (!wrap)             rm1 = fmaxf(rm1, bq.x);   // x1>=1
                if (!wrap && x0 >= 1)  rm1 = fmaxf(rm1, aq.y);   // x1>=2
                if (wrap || x0 <= 20)  rm1 = fmaxf(rm1, cq.x);   // x1<=21
                if (wrap || x0 <= 19)  rm1 = fmaxf(rm1, cq.y);   // x1<=20
                f2_t rmv; rmv.x = rm0; rmv.y = rm1;
                *(f2_t*)(r + q) = rmv;          // 8B-aligned (q even)
                if (stm) *(f2_t*)(m + q) = bq;  // keep cur map for out_s
                bv2[c] = bq;
            }
        }
    };
    // col-window reads: q±23 are ODD float offsets -> must use 4B-aligned vec2
    // (ds_read2_b32); q, q±46 are even -> natural b64.
    auto colwin = [&](int q, f2_t* v) {
        v[0] = *(const f2_t*)(r + q - 46);
        v[1] = *(const f2u_t*)(r + q - 23);
        v[2] = *(const f2_t*)(r + q);
        v[3] = *(const f2u_t*)(r + q + 23);
        v[4] = *(const f2_t*)(r + q + 46);
    };

    // ---------------- OLD map ----------------
    f2_t bo[PC];
    rmpass(sold, bo, false);
    WSYNC();
    float So = 0.f, Mor = 0.f, Moc = 0.f;
    float nd2 = INFINITY, ns = -INFINITY; int np = 0;
    #pragma unroll
    for (int c = 0; c < PC; c++) {
        int q = 128*c + 2*l;
        if (q < P_) {
            int y0 = q / W_, x0 = q - y0 * W_;
            bool wrap = (x0 == W_ - 1);
            int y1 = y0 + (wrap ? 1 : 0);
            f2_t v[5];
            colwin(q, v);
            float sm0 = v[2].x;
            if (y0 >= 1)  sm0 = fmaxf(sm0, v[1].x);
            if (y0 >= 2)  sm0 = fmaxf(sm0, v[0].x);
            if (y0 <= 21) sm0 = fmaxf(sm0, v[3].x);
            if (y0 <= 20) sm0 = fmaxf(sm0, v[4].x);
            float sm1 = v[2].y;
            if (y1 >= 1)  sm1 = fmaxf(sm1, v[1].y);
            if (y1 >= 2)  sm1 = fmaxf(sm1, v[0].y);
            if (y1 <= 21) sm1 = fmaxf(sm1, v[3].y);
            if (y1 <= 20) sm1 = fmaxf(sm1, v[4].y);
            float s0 = bo[c].x, s1 = bo[c].y;
            if (s0 == sm0 && s0 > TH_) {
                So += s0; Mor += s0 * (float)y0; Moc += s0 * (float)x0;
                int dy = gy - y0, dx = gx - x0;
                float d2 = (float)(dy*dy + dx*dx);
                if (d2 < nd2 || (d2 == nd2 && (s0 > ns || (s0 == ns && q < np)))) {
                    nd2 = d2; ns = s0; np = q;
                }
            }
            if (q + 1 < P_ && s1 == sm1 && s1 > TH_) {
                int x1 = wrap ? 0 : x0 + 1;
                So += s1; Mor += s1 * (float)y1; Moc += s1 * (float)x1;
                int dy = gy - y1, dx = gx - x1;
                float d2 = (float)(dy*dy + dx*dx);
                if (d2 < nd2 || (d2 == nd2 && (s1 > ns || (s1 == ns && q+1 < np)))) {
                    nd2 = d2; ns = s1; np = q + 1;
                }
            }
        }
    }
    #pragma unroll
    for (int d = 32; d > 0; d >>= 1) {
        So += __shfl_xor(So, d); Mor += __shfl_xor(Mor, d); Moc += __shfl_xor(Moc, d);
        float od2 = __shfl_xor(nd2, d), os = __shfl_xor(ns, d); int op = __shfl_xor(np, d);
        if (od2 < nd2 || (od2 == nd2 && (os > ns || (os == ns && op < np)))) {
            nd2 = od2; ns = os; np = op;
        }
    }
    const int cy = np / W_, cx = np - (np / W_) * W_;
    const float foldr = So * (float)cy - Mor;   // f_old (exactly 0 when no peaks)
    const float foldc = So * (float)cx - Moc;

    // ---------------- CUR map ----------------
    WSYNC();   // old eval's r reads done before cur rmpass overwrites r
    f2_t bc[PC];
    rmpass(scur, bc, true);
    WSYNC();
    float Sc = 0.f, Mcr = 0.f, Mcc = 0.f;
    int vb0 = 0, vb1 = 0;
    #pragma unroll
    for (int c = 0; c < PC; c++) {
        int q = 128*c + 2*l;
        if (q < P_) {
            int y0 = q / W_, x0 = q - y0 * W_;
            bool wrap = (x0 == W_ - 1);
            int y1 = y0 + (wrap ? 1 : 0);
            f2_t v[5];
            colwin(q, v);
            float sm0 = v[2].x;
            if (y0 >= 1)  sm0 = fmaxf(sm0, v[1].x);
            if (y0 >= 2)  sm0 = fmaxf(sm0, v[0].x);
            if (y0 <= 21) sm0 = fmaxf(sm0, v[3].x);
            if (y0 <= 20) sm0 = fmaxf(sm0, v[4].x);
            float sm1 = v[2].y;
            if (y1 >= 1)  sm1 = fmaxf(sm1, v[1].y);
            if (y1 >= 2)  sm1 = fmaxf(sm1, v[0].y);
            if (y1 <= 21) sm1 = fmaxf(sm1, v[3].y);
            if (y1 <= 20) sm1 = fmaxf(sm1, v[4].y);
            float s0 = bc[c].x, s1 = bc[c].y;
            if (s0 == sm0 && s0 > TH_) {
                vb0 |= 1 << c;
                Sc += s0; Mcr += s0 * (float)y0; Mcc += s0 * (float)x0;
            }
            if (q + 1 < P_ && s1 == sm1 && s1 > TH_) {
                vb1 |= 1 << c;
                int x1 = wrap ? 0 : x0 + 1;
                Sc += s1; Mcr += s1 * (float)y1; Mcc += s1 * (float)x1;
            }
        }
    }
    #pragma unroll
    for (int d = 32; d > 0; d >>= 1) {
        Sc += __shfl_xor(Sc, d); Mcr += __shfl_xor(Mcr, d); Mcc += __shfl_xor(Mcc, d);
    }
    WSYNC();   // cur eval's r reads done; reuse r as cs/cp/rk

    // ---------------- compaction via ballot (pair layout, p-ascending) ----------
    int K = 0;
    int nbp[PC];                      // #valid strictly before q, per pair-chunk
    #pragma unroll
    for (int c = 0; c < PC; c++) {
        bool v0 = (vb0 >> c) & 1, v1 = (vb1 >> c) & 1;
        unsigned long long bt0 = __ballot(v0), bt1 = __ballot(v1);
        int before = K + __popcll(bt0 & ltm) + __popcll(bt1 & ltm);
        nbp[c] = before;
        int q = 128*c + 2*l;
        if (v0 && before < CAP) { cs[before] = bc[c].x; cp[before] = q; }
        int my1 = before + (v0 ? 1 : 0);
        if (v1 && my1 < CAP)    { cs[my1] = bc[c].y;    cp[my1] = q + 1; }
        K += __popcll(bt0) + __popcll(bt1);
    }
    WSYNC();

    // ---------------- rank compacted peaks (r6 exact) ----------------
    const int Kc = K > CAP ? CAP : K;
    for (int i = l; i < Kc; i += 64) {
        float si = cs[i]; int pi = cp[i]; int rr = 0;
        for (int j = 0; j < Kc; j++) {
            float sj = cs[j]; int pj = cp[j];
            rr += (sj > si || (sj == si && pj < pi)) ? 1 : 0;
        }
        rk[i] = rr;
    }
    WSYNC();

    // ---------------- MLP over compacted peaks only (r6 exact) ----------------
    auto mlp = [&](int i, float& pv, int& rko) {
        int p = cp[i];
        float s = cs[i];
        rko = rk[i];
        int y = p / W_, x = p - (p / W_) * W_;
        float fcr = Sc * (float)y - Mcr;
        float fcc = Sc * (float)x - Mcc;
        float dr = foldr - fcr, dc = foldc - fcc;
        float err = sqrtf(fmaxf(dr*dr + dc*dc, 1e-24f));
        float h1[8];
        #pragma unroll
        for (int o = 0; o < 8; o++)
            h1[o] = fmaxf(fmaf(err, wt[2*o], fmaf(s, wt[2*o+1], wt[16+o])), 0.f);
        float pred = wt[104];
        #pragma unroll
        for (int o = 0; o < 8; o++) {
            float z = wt[88 + o];
            #pragma unroll
            for (int i2 = 0; i2 < 8; i2++) z = fmaf(h1[i2], wt[24 + o*8 + i2], z);
            pred = fmaf(fmaxf(z, 0.f), wt[96 + o], pred);
        }
        pv = pred;
    };
    float pv0 = 0.f, pv1 = 0.f; int rk0 = -1, rk1 = -1;
    if (l < Kc)      mlp(l, pv0, rk0);
    if (64 + l < Kc) mlp(64 + l, pv1, rk1);
    WSYNC();                      // all weight reads done before overlaying ps on wt
    if (rk0 >= 0) ps[rk0] = pv0;
    if (rk1 >= 0) ps[rk1] = pv1;

    // ---------------- slot per position (pair layout), then inv scatter ---------
    int sl0[PC], sl1[PC];
    #pragma unroll
    for (int c = 0; c < PC; c++) {
        int q = 128*c + 2*l;
        bool v0 = (vb0 >> c) & 1, v1 = (vb1 >> c) & 1;
        int nb0 = nbp[c];
        int nb1 = nb0 + (v0 ? 1 : 0);
        if (v0) sl0[c] = (nb0 < CAP) ? rk[nb0] : nb0; else sl0[c] = K + q - nb0;
        if (v1) sl1[c] = (nb1 < CAP) ? rk[nb1] : nb1; else sl1[c] = K + (q + 1) - nb1;
    }
    WSYNC();                      // rk reads done before ri overlays r
    #pragma unroll
    for (int c = 0; c < PC; c++) {
        int q = 128*c + 2*l;
        if (q < P_)     ri[sl0[c]] = q;
        if (q + 1 < P_) ri[sl1[c]] = q + 1;
    }
    WSYNC();

    // ---------------- linear, coalesced output (r6 exact) ----------------
    const size_t BP = (size_t)B * P_;
    float* out_pred = out;
    float* out_c    = out + BP;        // [B,P,2]
    float* out_s    = out + 3 * BP;
    float* out_v    = out + 4 * BP;
    const size_t rowbase = (size_t)b * P_;

    #pragma unroll
    for (int c = 0; c < NC; c++) {
        int j = 64*c + l;
        if (j < P_) {
            int p = ri[j];
            int y = p / W_, x = p - (p / W_) * W_;
            bool val = j < K;
            float pv = (val && j < CAP) ? ps[j] : 0.f;
            float s  = m[p];
            f2_t co; co.x = (float)y; co.y = (float)x;
            out_pred[rowbase + j] = pv;
            ((f2_t*)out_c)[rowbase + j] = co;
            out_s[rowbase + j] = s;
            out_v[rowbase + j] = val ? 1.f : 0.f;
        }
    }
}

extern "C" void kernel_launch(void* const* d_in, const int* in_sizes, int n_in,
                              void* d_out, int out_size, void* d_ws, size_t ws_size,
                              hipStream_t stream) {
    const int B = in_sizes[0] / (2 * P_);
    hipLaunchKernelGGL(peak_kernel, dim3((B + WPB - 1) / WPB), dim3(NTHR), 0, stream,
        (const float*)d_in[0], (const float*)d_in[1],
        (const float*)d_in[2], (const float*)d_in[3], (const float*)d_in[4],
        (const float*)d_in[5], (const float*)d_in[6], (const float*)d_in[7],
        (const float*)d_in[8], (const float*)d_in[9], (const float*)d_in[10],
        (const float*)d_in[11], (const float*)d_in[12], (const float*)d_in[13],
        (const float*)d_in[14], (const float*)d_in[15],
        (float*)d_out, B);
}